// Round 1
// 78.327 us; speedup vs baseline: 1.0073x; 1.0073x over previous
//
#include <hip/hip_runtime.h>
#include <math.h>

// out[b][s] = | prod_{k<4} cos((x[b][k] - sv[s][k]) * 0.5) |
// Identity: cos((a-b)/2) = cos(a/2)cos(b/2) + sin(a/2)sin(b/2)
//
// Output-write-bound (64 MiB fp32 out, 128 KiB in). Structure:
//  - each thread owns 4 support vectors: cos/sin half-angles computed ONCE
//    into 8 float4 registers (native trig; verified vs absmax threshold);
//  - the block's 8 x-rows' cos/sin live in LDS as float4 (ds_read_b128
//    wave-uniform broadcasts, conflict-free);
//  - compute ALL 8 output quads into registers first, then burst-store
//    8 coalesced dwordx4 back-to-back (max store-issue density, no
//    LDS/VALU interleaved in the store stream);
//  - grid (4, 512) = 2048 blocks = 8/CU for load balance.

#define BROWS 8

__device__ __forceinline__ float qprod(const float4& xc, const float4& xs,
                                       const float4& sc, const float4& ss) {
    float f0 = fmaf(xs.x, ss.x, xc.x * sc.x);
    float f1 = fmaf(xs.y, ss.y, xc.y * sc.y);
    float f2 = fmaf(xs.z, ss.z, xc.z * sc.z);
    float f3 = fmaf(xs.w, ss.w, xc.w * sc.w);
    return fabsf((f0 * f1) * (f2 * f3));
}

__global__ __launch_bounds__(256) void quantum_kernel(
    const float*  __restrict__ x,    // [B][4]
    const float4* __restrict__ sv,   // [S] float4
    float4* __restrict__ out,        // [B][S/4]
    int s_quads)
{
    __shared__ float4 xc_s[BROWS];   // per-row cos half-angles (4 comps)
    __shared__ float4 xs_s[BROWS];   // per-row sin half-angles

    const int tid = threadIdx.x;
    const int q   = blockIdx.x * blockDim.x + tid;   // s-quad index (exact grid)
    const int b0  = blockIdx.y * BROWS;

    // Cooperative x-row half-angle cos/sin: 8 rows x 4 comps = 32 lanes.
    // Layout: ((float*)xc_s)[row*4+comp] == xc_s[row].{x,y,z,w}
    if (tid < BROWS * 4) {
        const float a = x[(size_t)b0 * 4 + tid] * 0.5f;
        ((float*)xc_s)[tid] = __cosf(a);
        ((float*)xs_s)[tid] = __sinf(a);
    }

    // This thread's 4 support vectors -> cos/sin register cache.
    float4 sc[4], ss[4];
#pragma unroll
    for (int j = 0; j < 4; ++j) {
        const float4 v = sv[(size_t)4 * q + j];
        sc[j].x = __cosf(v.x * 0.5f);  ss[j].x = __sinf(v.x * 0.5f);
        sc[j].y = __cosf(v.y * 0.5f);  ss[j].y = __sinf(v.y * 0.5f);
        sc[j].z = __cosf(v.z * 0.5f);  ss[j].z = __sinf(v.z * 0.5f);
        sc[j].w = __cosf(v.w * 0.5f);  ss[j].w = __sinf(v.w * 0.5f);
    }

    __syncthreads();

    // Phase 1: compute all BROWS output quads into registers.
    float4 r[BROWS];
#pragma unroll
    for (int i = 0; i < BROWS; ++i) {
        const float4 xc = xc_s[i];   // ds_read_b128 broadcast
        const float4 xs = xs_s[i];
        r[i].x = qprod(xc, xs, sc[0], ss[0]);
        r[i].y = qprod(xc, xs, sc[1], ss[1]);
        r[i].z = qprod(xc, xs, sc[2], ss[2]);
        r[i].w = qprod(xc, xs, sc[3], ss[3]);
    }

    // Phase 2: burst store — back-to-back coalesced dwordx4, nothing between.
    float4* __restrict__ orow = out + (size_t)b0 * s_quads + q;
#pragma unroll
    for (int i = 0; i < BROWS; ++i)
        orow[(size_t)i * s_quads] = r[i];
}

extern "C" void kernel_launch(void* const* d_in, const int* in_sizes, int n_in,
                              void* d_out, int out_size, void* d_ws, size_t ws_size,
                              hipStream_t stream) {
    const float*  x  = (const float*)d_in[0];    // [B,4] fp32
    const float4* sv = (const float4*)d_in[1];   // [S,4] fp32
    float4* out = (float4*)d_out;                // [B,S] fp32

    const int B = in_sizes[0] / 4;
    const int S = in_sizes[1] / 4;
    const int s_quads = S / 4;                   // 1024 for S=4096

    const int block = 256;
    dim3 grid(s_quads / block, B / BROWS);       // (4, 512) — exact for 4096
    quantum_kernel<<<grid, block, 0, stream>>>(x, sv, out, s_quads);
}